// Round 20
// baseline (82.692 us; speedup 1.0000x reference)
//
#include <hip/hip_runtime.h>
#include <stdint.h>

#define IMG_B 256
#define IMG_H 224
#define IMG_W 224
#define HWPIX 50176
#define YP 228   // kA1 LDS row pitch in dwords (224 data + 4 pad)

// exact IEEE f32 ops, no contraction, matching numpy's elementwise semantics
#define FA(a,b) __fadd_rn((a),(b))
#define FM(a,b) __fmul_rn((a),(b))
#define FS(a,b) __fsub_rn((a),(b))
#define FD(a,b) __fdiv_rn((a),(b))

typedef float nt4 __attribute__((ext_vector_type(4)));

// python-float scalars cast to f32 exactly as numpy weak-scalar promotion does
__device__ __forceinline__ float VBF()   { return (float)(9.0/30.0*(1.9-0.1)+0.1); }
__device__ __forceinline__ float OMVBF() { return (float)(1.0 - (9.0/30.0*(1.9-0.1)+0.1)); }
__device__ __forceinline__ float VSF()   { return (float)(9.0/30.0*1.0); }

// exact blur fold (9 terms, raster order) + y1 blend, for 4 pixels
__device__ __forceinline__ void y1_from_rows(const float* yU, const float* yC,
                                             const float* yD, float* y1o) {
    const float WN = 1.0f / 13.0f, WC = 5.0f / 13.0f;
#pragma unroll
    for (int mm = 0; mm < 4; ++mm) {
        float acc = 0.0f;
        acc = FA(acc, FM(WN, yU[mm + 0]));
        acc = FA(acc, FM(WN, yU[mm + 1]));
        acc = FA(acc, FM(WN, yU[mm + 2]));
        acc = FA(acc, FM(WN, yC[mm + 0]));
        acc = FA(acc, FM(WC, yC[mm + 1]));
        acc = FA(acc, FM(WN, yC[mm + 2]));
        acc = FA(acc, FM(WN, yD[mm + 0]));
        acc = FA(acc, FM(WN, yD[mm + 1]));
        acc = FA(acc, FM(WN, yD[mm + 2]));
        y1o[mm] = FA(FM(yC[mm + 1], VBF()), FM(acc, OMVBF()));
    }
}

// kB tap reader: raw-x taps from LDS, converted to y = s*x+m at read time.
// Row-invalid -> y6 all 0 (conv zero-pads y); col pads via guards. Bit-exact.
__device__ __forceinline__ void ldsx_y6(const float* __restrict__ r, int j,
                                        bool rowvalid, float s, float m, float* y6) {
    if (!rowvalid) {
#pragma unroll
        for (int q = 0; q < 6; ++q) y6[q] = 0.0f;
        return;
    }
    const float4 vC = *(const float4*)(r + j);
    const float4 vL = *(const float4*)(r + (j > 0 ? j - 4 : 0));
    const float4 vR = *(const float4*)(r + (j + 4 < IMG_W ? j + 4 : IMG_W - 4));
    y6[0] = (j > 0) ? FA(FM(vL.w, s), m) : 0.0f;
    y6[1] = FA(FM(vC.x, s), m);
    y6[2] = FA(FM(vC.y, s), m);
    y6[3] = FA(FM(vC.z, s), m);
    y6[4] = FA(FM(vC.w, s), m);
    y6[5] = (j + 4 < IMG_W) ? FA(FM(vR.x, s), m) : 0.0f;
}

// ---- Kernel A1 (R16 structure + XCD swizzle + shfl tree tail): one block =
// one 3136-px chunk (14 rows) = 32 aligned leaves. GRAY-FIRST. 12 global f4
// loads/thread in flight, gray folded in regs, ONE LDS plane [16][YP].
__global__ __launch_bounds__(256, 4) void kA1(const float* __restrict__ x,
                                              const float* __restrict__ mean_,
                                              const float* __restrict__ std_,
                                              float* __restrict__ part) {
    // bijective XCD swizzle (4096 % 8 == 0)
    const int swz = (blockIdx.x & 7) * 512 + (blockIdx.x >> 3);
    const int ck = swz & 15, b = swz >> 4;
    const int t = threadIdx.x;
    const int r0 = ck * 14;

    __shared__ float SM[3648];        // Y[16][YP] staging; G2/CH alias after
    float* Y  = SM;
    float* G2 = SM;                   // [0,3328) leaf-padded gray(y1)
    float* CH = SM + 3328;            // [3328,3584)

    const int rg  = t / 56;
    const int col = t - rg * 56;
    const bool active = (t < 224);
    const int rcount = (rg < 2) ? 4 : 3;                      // rows 4,4,3,3
    const int rstart = (rg < 2) ? rg * 4 : 8 + (rg - 2) * 3;  // 0,4,8,11
    const int jd = col * 4;
    const bool lwave = ((t & 63) == 0)  && (col > 0);
    const bool rwave = ((t & 63) == 63) && (col < 55);

    const float s0 = std_[0], s1 = std_[1], s2 = std_[2];
    const float m0 = mean_[0], m1 = mean_[1], m2 = mean_[2];
    const float C0 = 0.299f, C1 = 0.587f, C2 = 0.114f;

    // ---- stage: all 12 loads in flight, fold to gray, one LDS plane ----
    float4 q0[4], q1[4], q2[4];
#pragma unroll
    for (int u = 0; u < 4; ++u) {
        const int idx = t + 256 * u;
        q0[u] = q1[u] = q2[u] = make_float4(0.f, 0.f, 0.f, 0.f);
        if (idx < 896) {
            const int row = idx / 56, c4 = (idx % 56) * 4;
            const int gi = r0 - 1 + row;
            if (gi >= 0 && gi < IMG_H) {
                const float* p = x + (size_t)b * 3 * HWPIX + (size_t)gi * IMG_W + c4;
                q0[u] = *(const float4*)(p);
                q1[u] = *(const float4*)(p + HWPIX);
                q2[u] = *(const float4*)(p + 2 * HWPIX);
            }
        }
    }
#define GRAY1(a0v, a1v, a2v)                                              \
    FA(FA(FM(C0, FA(FM(a0v, s0), m0)), FM(C1, FA(FM(a1v, s1), m1))),      \
       FM(C2, FA(FM(a2v, s2), m2)))
#pragma unroll
    for (int u = 0; u < 4; ++u) {
        const int idx = t + 256 * u;
        if (idx < 896) {
            const int row = idx / 56, c4 = (idx % 56) * 4;
            const int gi = r0 - 1 + row;
            float4 w = make_float4(0.f, 0.f, 0.f, 0.f);
            if (gi >= 0 && gi < IMG_H) {
                w.x = GRAY1(q0[u].x, q1[u].x, q2[u].x);
                w.y = GRAY1(q0[u].y, q1[u].y, q2[u].y);
                w.z = GRAY1(q0[u].z, q1[u].z, q2[u].z);
                w.w = GRAY1(q0[u].w, q1[u].w, q2[u].w);
            }
            *(float4*)(&Y[row * YP + c4]) = w;
        }
    }
#undef GRAY1
    __syncthreads();

#define LOADROW(V, LWv, RWv, yr) do {                                 \
        V   = *(const float4*)(&Y[(yr) * YP + jd]);                   \
        LWv = __shfl_up(V.w, 1, 64);                                  \
        RWv = __shfl_down(V.x, 1, 64);                                \
        if (lwave) LWv = Y[(yr) * YP + jd - 1];                       \
        if (rwave) RWv = Y[(yr) * YP + jd + 4];                       \
    } while (0)

#define FILL6(y6, V, LWv, RWv) do {                                   \
        y6[0] = (col > 0) ? LWv : 0.0f;                               \
        y6[1] = V.x; y6[2] = V.y; y6[3] = V.z; y6[4] = V.w;           \
        y6[5] = (col < 55) ? RWv : 0.0f;                              \
    } while (0)

    float4 gacc[4];

    // ---- single-channel column sweep: gacc = gray(y1) ----
    if (active) {
        float4 v0, v1, v2;
        float la0, la1, la2, ra0, ra1, ra2;
        LOADROW(v0, la0, ra0, rstart);
        LOADROW(v1, la1, ra1, rstart + 1);
#pragma unroll
        for (int k = 0; k < 4; ++k) {
            if (k < rcount) {
                LOADROW(v2, la2, ra2, rstart + k + 2);
                float yU[6], yC[6], yD[6], y1g[4];
                FILL6(yU, v0, la0, ra0);
                FILL6(yC, v1, la1, ra1);
                FILL6(yD, v2, la2, ra2);
                y1_from_rows(yU, yC, yD, y1g);
                gacc[k].x = y1g[0]; gacc[k].y = y1g[1];
                gacc[k].z = y1g[2]; gacc[k].w = y1g[3];
                v0 = v1; la0 = la1; ra0 = ra1;
                v1 = v2; la1 = la2; ra1 = ra2;
            }
        }
    }
    __syncthreads();   // Y dead -> G2 alias handoff

    // ---- write gray(y1) into leaf-padded G2 (aliases dead Y) ----
    if (active) {
#pragma unroll
        for (int k = 0; k < 4; ++k) {
            if (k < rcount) {
                const int pl = (rstart + k) * IMG_W + jd;
                const int grp = pl / 392;
                const int rem = pl - grp * 392;
                int li = rem / 96; if (li > 3) li = 3;
                const int o = rem - 96 * li;
                *(float4*)(&G2[(grp * 4 + li) * 104 + o]) = gacc[k];
            }
        }
    }
    __syncthreads();

    // ---- 8 chains per leaf (exact numpy base case) ----
    {
        const int leaf = t >> 3, e = t & 7;
        const int base = leaf * 104 + e;
        const int nk = ((leaf & 3) == 3) ? 13 : 12;
        float r = G2[base];
        for (int k = 1; k < nk; ++k) r = FA(r, G2[base + 8 * k]);
        CH[t] = r;   // t == leaf*8+e
    }
    __syncthreads();

    // ---- leaf sums + exact 5-level binary tree, wave-parallel via shfl ----
    // lane l<32 of wave 0 holds leaf sum l; each level lane l<n computes
    // FA(v[2l], v[2l+1]) — identical pairing to the serial tree (bit-exact).
    // Consumers at level n only read lanes < 2n, which hold valid data.
    if (t < 32) {
        const float* c8 = &CH[t * 8];
        float vv = FA(FA(FA(c8[0], c8[1]), FA(c8[2], c8[3])),
                      FA(FA(c8[4], c8[5]), FA(c8[6], c8[7])));
#pragma unroll
        for (int n = 16; n >= 1; n >>= 1) {
            const float lo = __shfl(vv, 2 * t, 64);
            const float hi = __shfl(vv, 2 * t + 1, 64);
            vv = FA(lo, hi);
        }
        if (t == 0) part[swz] = vv;
    }
#undef LOADROW
#undef FILL6
}

// ---- Kernel B: 1-D grid (12288 blocks), XCD swizzle; one block = one 14-row
// chunk of one (b,c). Staging via ASYNC global_load_lds (raw x, linear LDS:
// offset == idx*16B since 56 quads * 4 == IMG_W); y = s*x+m applied at tap
// read (bit-identical expression). gm fold overlaps the DMA. NT stores. ----
__global__ __launch_bounds__(256) void kB(const float* __restrict__ x,
                                          const float* __restrict__ mean_,
                                          const float* __restrict__ std_,
                                          const float* __restrict__ part,
                                          float* __restrict__ out) {
    const int swz = ((int)blockIdx.x & 7) * 1536 + ((int)blockIdx.x >> 3);
    const int ck = swz & 15;
    const int r1 = swz >> 4;
    const int c  = r1 % 3;
    const int b  = r1 / 3;
    const int t  = threadIdx.x;
    const int r0 = ck * 14;

    __shared__ float X[16 * IMG_W];   // raw x rows r0-1 .. r0+14 (clamped)
    __shared__ float gsh;

    const float s = std_[c], m = mean_[c];
    const float* xc = x + (size_t)(b * 3 + c) * HWPIX;

    // ---- async stage: 896 float4 DMAs, LDS linear in idx (all-active waves:
    // 896 = 14*64, so each wave's 64 lanes are contiguous; dest = idx*16B) ----
#pragma unroll
    for (int u = 0; u < 4; ++u) {
        const int idx = t + 256 * u;
        if (idx < 896) {
            int gi = r0 - 1 + idx / 56;
            gi = gi < 0 ? 0 : (gi > IMG_H - 1 ? IMG_H - 1 : gi);   // clamp: safe addr,
            const float* src = xc + (size_t)gi * IMG_W + (idx % 56) * 4; // garbage rows
            __builtin_amdgcn_global_load_lds(                      // masked at read
                (const __attribute__((address_space(1))) uint32_t*)src,
                (__attribute__((address_space(3))) uint32_t*)(&X[(size_t)idx * 4]),
                16, 0, 0);
        }
    }

    if (t == 0) {
        // exact 4-level fold of the 16 chunk roots, / 50176 (overlaps DMA)
        float v[16];
#pragma unroll
        for (int k = 0; k < 16; ++k) v[k] = part[b * 16 + k];
#pragma unroll
        for (int n = 8; n >= 1; n >>= 1)
#pragma unroll
            for (int k = 0; k < 8; ++k)
                if (k < n) v[k] = FA(v[2 * k], v[2 * k + 1]);
        gsh = FD(v[0], 50176.0f);
    }
    __syncthreads();   // drains vmcnt (DMA complete) + publishes gsh
    const float g = gsh;

    float* oc = out + (size_t)(b * 3 + c) * HWPIX + (size_t)r0 * IMG_W;

    for (int qi = t; qi < 784; qi += 256) {
        const int lr = qi / 56 + 1, j = (qi % 56) * 4;
        const int gU = r0 + lr - 2, gD = r0 + lr;   // global rows of taps U/D
        float yU[6], yC[6], yD[6], y1[4];
        ldsx_y6(&X[(lr - 1) * IMG_W], j, (gU >= 0),     s, m, yU);
        ldsx_y6(&X[lr * IMG_W],       j, true,          s, m, yC);
        ldsx_y6(&X[(lr + 1) * IMG_W], j, (gD < IMG_H),  s, m, yD);
        y1_from_rows(yU, yC, yD, y1);

        nt4 o4;
#pragma unroll
        for (int mm = 0; mm < 4; ++mm) {
            const float y2 = FA(FM(y1[mm], VBF()), FM(g, OMVBF()));
            const float y3 = FM(y2, VBF());
            const float y4 = (y3 < VSF()) ? y3 : FS(1.0f, y3);
            o4[mm] = FD(FS(y4, m), s);
        }
        __builtin_nontemporal_store(o4, (nt4*)(oc + (size_t)(lr - 1) * IMG_W + j));
    }
}

extern "C" void kernel_launch(void* const* d_in, const int* in_sizes, int n_in,
                              void* d_out, int out_size, void* d_ws, size_t ws_size,
                              hipStream_t stream) {
    const float* x     = (const float*)d_in[0];
    const float* mean_ = (const float*)d_in[1];
    const float* std_  = (const float*)d_in[2];
    float* out = (float*)d_out;

    float* part = (float*)d_ws;   // 4096 f32 (16 chunk roots x 256 images)

    kA1<<<IMG_B * 16, 256, 0, stream>>>(x, mean_, std_, part);

    kB<<<IMG_B * 3 * 16, 256, 0, stream>>>(x, mean_, std_, part, out);
}

// Round 21
// 76.764 us; speedup vs baseline: 1.0772x; 1.0772x over previous
//
#include <hip/hip_runtime.h>

#define IMG_B 256
#define IMG_H 224
#define IMG_W 224
#define HWPIX 50176
#define YP 228   // kA1 LDS row pitch in dwords (224 data + 4 pad)

// exact IEEE f32 ops, no contraction, matching numpy's elementwise semantics
#define FA(a,b) __fadd_rn((a),(b))
#define FM(a,b) __fmul_rn((a),(b))
#define FS(a,b) __fsub_rn((a),(b))
#define FD(a,b) __fdiv_rn((a),(b))

typedef float nt4 __attribute__((ext_vector_type(4)));

// python-float scalars cast to f32 exactly as numpy weak-scalar promotion does
__device__ __forceinline__ float VBF()   { return (float)(9.0/30.0*(1.9-0.1)+0.1); }
__device__ __forceinline__ float OMVBF() { return (float)(1.0 - (9.0/30.0*(1.9-0.1)+0.1)); }
__device__ __forceinline__ float VSF()   { return (float)(9.0/30.0*1.0); }

// exact blur fold (9 terms, raster order) + y1 blend, for 4 pixels
__device__ __forceinline__ void y1_from_rows(const float* yU, const float* yC,
                                             const float* yD, float* y1o) {
    const float WN = 1.0f / 13.0f, WC = 5.0f / 13.0f;
#pragma unroll
    for (int mm = 0; mm < 4; ++mm) {
        float acc = 0.0f;
        acc = FA(acc, FM(WN, yU[mm + 0]));
        acc = FA(acc, FM(WN, yU[mm + 1]));
        acc = FA(acc, FM(WN, yU[mm + 2]));
        acc = FA(acc, FM(WN, yC[mm + 0]));
        acc = FA(acc, FM(WC, yC[mm + 1]));
        acc = FA(acc, FM(WN, yC[mm + 2]));
        acc = FA(acc, FM(WN, yD[mm + 0]));
        acc = FA(acc, FM(WN, yD[mm + 1]));
        acc = FA(acc, FM(WN, yD[mm + 2]));
        y1o[mm] = FA(FM(yC[mm + 1], VBF()), FM(acc, OMVBF()));
    }
}

// prefetch raw x float4s for the 896 staged quads (rows r0-1..r0+14) into regs (kB)
__device__ __forceinline__ void stage_load(const float* __restrict__ xc, int r0,
                                           int t, float4* pf) {
#pragma unroll
    for (int u = 0; u < 4; ++u) {
        const int idx = t + 256 * u;
        float4 v = make_float4(0.f, 0.f, 0.f, 0.f);
        if (idx < 896) {
            const int row = idx / 56, c4 = (idx % 56) * 4;
            const int gi = r0 - 1 + row;
            if (gi >= 0 && gi < IMG_H)
                v = *(const float4*)(xc + (size_t)gi * IMG_W + c4);
        }
        pf[u] = v;
    }
}

// write y = s*x+m to LDS (pitch P dwords) from prefetched regs; pad rows -> 0 (kB)
__device__ __forceinline__ void stage_write(float s, float m, int r0, int t,
                                            const float4* pf, float* __restrict__ Y,
                                            int P) {
#pragma unroll
    for (int u = 0; u < 4; ++u) {
        const int idx = t + 256 * u;
        if (idx < 896) {
            const int row = idx / 56, c4 = (idx % 56) * 4;
            const int gi = r0 - 1 + row;
            float4 w;
            if (gi >= 0 && gi < IMG_H) {
                w.x = FA(FM(pf[u].x, s), m);
                w.y = FA(FM(pf[u].y, s), m);
                w.z = FA(FM(pf[u].z, s), m);
                w.w = FA(FM(pf[u].w, s), m);
            } else {
                w.x = w.y = w.z = w.w = 0.0f;
            }
            *(float4*)(&Y[row * P + c4]) = w;
        }
    }
}

// 6 y-taps from LDS (kB only; pitch 224): aligned float4 reads
__device__ __forceinline__ void lds_y6(const float* __restrict__ r, int j, float* y6) {
    const float4 vC = *(const float4*)(r + j);
    const float4 vL = *(const float4*)(r + (j > 0 ? j - 4 : 0));
    const float4 vR = *(const float4*)(r + (j + 4 < IMG_W ? j + 4 : IMG_W - 4));
    y6[0] = (j > 0) ? vL.w : 0.0f;
    y6[1] = vC.x; y6[2] = vC.y; y6[3] = vC.z; y6[4] = vC.w;
    y6[5] = (j + 4 < IMG_W) ? vR.x : 0.0f;
}

// ---- Kernel A1 (R16 structure + XCD swizzle + shfl tree tail): one block =
// one 3136-px chunk (14 rows) = 32 aligned leaves. GRAY-FIRST. 12 global f4
// loads/thread in flight, gray folded in regs, ONE LDS plane [16][YP].
__global__ __launch_bounds__(256, 4) void kA1(const float* __restrict__ x,
                                              const float* __restrict__ mean_,
                                              const float* __restrict__ std_,
                                              float* __restrict__ part) {
    // bijective XCD swizzle (4096 % 8 == 0): each XCD gets 32 whole images
    const int swz = (blockIdx.x & 7) * 512 + (blockIdx.x >> 3);
    const int ck = swz & 15, b = swz >> 4;
    const int t = threadIdx.x;
    const int r0 = ck * 14;

    __shared__ float SM[3648];        // Y[16][YP] staging; G2/CH alias after
    float* Y  = SM;
    float* G2 = SM;                   // [0,3328) leaf-padded gray(y1)
    float* CH = SM + 3328;            // [3328,3584)

    const int rg  = t / 56;
    const int col = t - rg * 56;
    const bool active = (t < 224);
    const int rcount = (rg < 2) ? 4 : 3;                      // rows 4,4,3,3
    const int rstart = (rg < 2) ? rg * 4 : 8 + (rg - 2) * 3;  // 0,4,8,11
    const int jd = col * 4;
    const bool lwave = ((t & 63) == 0)  && (col > 0);
    const bool rwave = ((t & 63) == 63) && (col < 55);

    const float s0 = std_[0], s1 = std_[1], s2 = std_[2];
    const float m0 = mean_[0], m1 = mean_[1], m2 = mean_[2];
    const float C0 = 0.299f, C1 = 0.587f, C2 = 0.114f;

    // ---- stage: all 12 loads in flight, fold to gray, one LDS plane ----
    float4 q0[4], q1[4], q2[4];
#pragma unroll
    for (int u = 0; u < 4; ++u) {
        const int idx = t + 256 * u;
        q0[u] = q1[u] = q2[u] = make_float4(0.f, 0.f, 0.f, 0.f);
        if (idx < 896) {
            const int row = idx / 56, c4 = (idx % 56) * 4;
            const int gi = r0 - 1 + row;
            if (gi >= 0 && gi < IMG_H) {
                const float* p = x + (size_t)b * 3 * HWPIX + (size_t)gi * IMG_W + c4;
                q0[u] = *(const float4*)(p);
                q1[u] = *(const float4*)(p + HWPIX);
                q2[u] = *(const float4*)(p + 2 * HWPIX);
            }
        }
    }
#define GRAY1(a0v, a1v, a2v)                                              \
    FA(FA(FM(C0, FA(FM(a0v, s0), m0)), FM(C1, FA(FM(a1v, s1), m1))),      \
       FM(C2, FA(FM(a2v, s2), m2)))
#pragma unroll
    for (int u = 0; u < 4; ++u) {
        const int idx = t + 256 * u;
        if (idx < 896) {
            const int row = idx / 56, c4 = (idx % 56) * 4;
            const int gi = r0 - 1 + row;
            float4 w = make_float4(0.f, 0.f, 0.f, 0.f);
            if (gi >= 0 && gi < IMG_H) {
                w.x = GRAY1(q0[u].x, q1[u].x, q2[u].x);
                w.y = GRAY1(q0[u].y, q1[u].y, q2[u].y);
                w.z = GRAY1(q0[u].z, q1[u].z, q2[u].z);
                w.w = GRAY1(q0[u].w, q1[u].w, q2[u].w);
            }
            *(float4*)(&Y[row * YP + c4]) = w;
        }
    }
#undef GRAY1
    __syncthreads();

#define LOADROW(V, LWv, RWv, yr) do {                                 \
        V   = *(const float4*)(&Y[(yr) * YP + jd]);                   \
        LWv = __shfl_up(V.w, 1, 64);                                  \
        RWv = __shfl_down(V.x, 1, 64);                                \
        if (lwave) LWv = Y[(yr) * YP + jd - 1];                       \
        if (rwave) RWv = Y[(yr) * YP + jd + 4];                       \
    } while (0)

#define FILL6(y6, V, LWv, RWv) do {                                   \
        y6[0] = (col > 0) ? LWv : 0.0f;                               \
        y6[1] = V.x; y6[2] = V.y; y6[3] = V.z; y6[4] = V.w;           \
        y6[5] = (col < 55) ? RWv : 0.0f;                              \
    } while (0)

    float4 gacc[4];

    // ---- single-channel column sweep: gacc = gray(y1) ----
    if (active) {
        float4 v0, v1, v2;
        float la0, la1, la2, ra0, ra1, ra2;
        LOADROW(v0, la0, ra0, rstart);
        LOADROW(v1, la1, ra1, rstart + 1);
#pragma unroll
        for (int k = 0; k < 4; ++k) {
            if (k < rcount) {
                LOADROW(v2, la2, ra2, rstart + k + 2);
                float yU[6], yC[6], yD[6], y1g[4];
                FILL6(yU, v0, la0, ra0);
                FILL6(yC, v1, la1, ra1);
                FILL6(yD, v2, la2, ra2);
                y1_from_rows(yU, yC, yD, y1g);
                gacc[k].x = y1g[0]; gacc[k].y = y1g[1];
                gacc[k].z = y1g[2]; gacc[k].w = y1g[3];
                v0 = v1; la0 = la1; ra0 = ra1;
                v1 = v2; la1 = la2; ra1 = ra2;
            }
        }
    }
    __syncthreads();   // Y dead -> G2 alias handoff

    // ---- write gray(y1) into leaf-padded G2 (aliases dead Y) ----
    if (active) {
#pragma unroll
        for (int k = 0; k < 4; ++k) {
            if (k < rcount) {
                const int pl = (rstart + k) * IMG_W + jd;
                const int grp = pl / 392;
                const int rem = pl - grp * 392;
                int li = rem / 96; if (li > 3) li = 3;
                const int o = rem - 96 * li;
                *(float4*)(&G2[(grp * 4 + li) * 104 + o]) = gacc[k];
            }
        }
    }
    __syncthreads();

    // ---- 8 chains per leaf (exact numpy base case) ----
    {
        const int leaf = t >> 3, e = t & 7;
        const int base = leaf * 104 + e;
        const int nk = ((leaf & 3) == 3) ? 13 : 12;
        float r = G2[base];
        for (int k = 1; k < nk; ++k) r = FA(r, G2[base + 8 * k]);
        CH[t] = r;   // t == leaf*8+e
    }
    __syncthreads();

    // ---- leaf sums + exact 5-level binary tree, wave-parallel via shfl ----
    // lane l<32 of wave 0 holds leaf sum l; each level lane l computes
    // FA(v[2l], v[2l+1]) — identical pairing to the serial tree (bit-exact).
    if (t < 32) {
        const float* c8 = &CH[t * 8];
        float vv = FA(FA(FA(c8[0], c8[1]), FA(c8[2], c8[3])),
                      FA(FA(c8[4], c8[5]), FA(c8[6], c8[7])));
#pragma unroll
        for (int n = 16; n >= 1; n >>= 1) {
            const float lo = __shfl(vv, 2 * t, 64);
            const float hi = __shfl(vv, 2 * t + 1, 64);
            vv = FA(lo, hi);
        }
        if (t == 0) part[swz] = vv;
    }
#undef LOADROW
#undef FILL6
}

// ---- Kernel B (R19 structure, reg-staged): 1-D grid (12288 blocks), XCD
// swizzle; one block = one 14-row chunk of one (b,c). gm fold hoisted BEFORE
// stage_write so the 16 part[] loads overlap the x-load latency. NT stores. ----
__global__ __launch_bounds__(256) void kB(const float* __restrict__ x,
                                          const float* __restrict__ mean_,
                                          const float* __restrict__ std_,
                                          const float* __restrict__ part,
                                          float* __restrict__ out) {
    // bijective XCD swizzle (12288 % 8 == 0)
    const int swz = ((int)blockIdx.x & 7) * 1536 + ((int)blockIdx.x >> 3);
    const int ck = swz & 15;
    const int r1 = swz >> 4;
    const int c  = r1 % 3;
    const int b  = r1 / 3;
    const int t  = threadIdx.x;
    const int r0 = ck * 14;

    __shared__ float Y[16 * IMG_W];
    __shared__ float gsh;

    const float s = std_[c], m = mean_[c];
    float4 pf[4];
    stage_load(x + (size_t)(b * 3 + c) * HWPIX, r0, t, pf);

    if (t == 0) {
        // exact 4-level fold of the 16 chunk roots, / 50176
        // (issued while the x stage loads are still in flight)
        float v[16];
#pragma unroll
        for (int k = 0; k < 16; ++k) v[k] = part[b * 16 + k];
#pragma unroll
        for (int n = 8; n >= 1; n >>= 1)
#pragma unroll
            for (int k = 0; k < 8; ++k)
                if (k < n) v[k] = FA(v[2 * k], v[2 * k + 1]);
        gsh = FD(v[0], 50176.0f);
    }

    stage_write(s, m, r0, t, pf, Y, IMG_W);
    __syncthreads();
    const float g = gsh;

    float* oc = out + (size_t)(b * 3 + c) * HWPIX + (size_t)r0 * IMG_W;

    for (int qi = t; qi < 784; qi += 256) {
        const int lr = qi / 56 + 1, j = (qi % 56) * 4;
        float yU[6], yC[6], yD[6], y1[4];
        lds_y6(&Y[(lr - 1) * IMG_W], j, yU);
        lds_y6(&Y[lr * IMG_W],       j, yC);
        lds_y6(&Y[(lr + 1) * IMG_W], j, yD);
        y1_from_rows(yU, yC, yD, y1);

        nt4 o4;
#pragma unroll
        for (int mm = 0; mm < 4; ++mm) {
            const float y2 = FA(FM(y1[mm], VBF()), FM(g, OMVBF()));
            const float y3 = FM(y2, VBF());
            const float y4 = (y3 < VSF()) ? y3 : FS(1.0f, y3);
            o4[mm] = FD(FS(y4, m), s);
        }
        __builtin_nontemporal_store(o4, (nt4*)(oc + (size_t)(lr - 1) * IMG_W + j));
    }
}

extern "C" void kernel_launch(void* const* d_in, const int* in_sizes, int n_in,
                              void* d_out, int out_size, void* d_ws, size_t ws_size,
                              hipStream_t stream) {
    const float* x     = (const float*)d_in[0];
    const float* mean_ = (const float*)d_in[1];
    const float* std_  = (const float*)d_in[2];
    float* out = (float*)d_out;

    float* part = (float*)d_ws;   // 4096 f32 (16 chunk roots x 256 images)

    kA1<<<IMG_B * 16, 256, 0, stream>>>(x, mean_, std_, part);

    kB<<<IMG_B * 3 * 16, 256, 0, stream>>>(x, mean_, std_, part, out);
}

// Round 22
// 75.652 us; speedup vs baseline: 1.0931x; 1.0147x over previous
//
#include <hip/hip_runtime.h>

#define IMG_B 256
#define IMG_H 224
#define IMG_W 224
#define HWPIX 50176
#define YP 228   // kA1 LDS row pitch in dwords (224 data + 4 pad)

// exact IEEE f32 ops, no contraction, matching numpy's elementwise semantics
#define FA(a,b) __fadd_rn((a),(b))
#define FM(a,b) __fmul_rn((a),(b))
#define FS(a,b) __fsub_rn((a),(b))
#define FD(a,b) __fdiv_rn((a),(b))

typedef float nt4 __attribute__((ext_vector_type(4)));

// python-float scalars cast to f32 exactly as numpy weak-scalar promotion does
__device__ __forceinline__ float VBF()   { return (float)(9.0/30.0*(1.9-0.1)+0.1); }
__device__ __forceinline__ float OMVBF() { return (float)(1.0 - (9.0/30.0*(1.9-0.1)+0.1)); }
__device__ __forceinline__ float VSF()   { return (float)(9.0/30.0*1.0); }

// exact blur fold (9 terms, raster order) + y1 blend, for 4 pixels
__device__ __forceinline__ void y1_from_rows(const float* yU, const float* yC,
                                             const float* yD, float* y1o) {
    const float WN = 1.0f / 13.0f, WC = 5.0f / 13.0f;
#pragma unroll
    for (int mm = 0; mm < 4; ++mm) {
        float acc = 0.0f;
        acc = FA(acc, FM(WN, yU[mm + 0]));
        acc = FA(acc, FM(WN, yU[mm + 1]));
        acc = FA(acc, FM(WN, yU[mm + 2]));
        acc = FA(acc, FM(WN, yC[mm + 0]));
        acc = FA(acc, FM(WC, yC[mm + 1]));
        acc = FA(acc, FM(WN, yC[mm + 2]));
        acc = FA(acc, FM(WN, yD[mm + 0]));
        acc = FA(acc, FM(WN, yD[mm + 1]));
        acc = FA(acc, FM(WN, yD[mm + 2]));
        y1o[mm] = FA(FM(yC[mm + 1], VBF()), FM(acc, OMVBF()));
    }
}

// prefetch raw x float4s for the 896 staged quads (rows r0-1..r0+14) into regs (kB)
__device__ __forceinline__ void stage_load(const float* __restrict__ xc, int r0,
                                           int t, float4* pf) {
#pragma unroll
    for (int u = 0; u < 4; ++u) {
        const int idx = t + 256 * u;
        float4 v = make_float4(0.f, 0.f, 0.f, 0.f);
        if (idx < 896) {
            const int row = idx / 56, c4 = (idx % 56) * 4;
            const int gi = r0 - 1 + row;
            if (gi >= 0 && gi < IMG_H)
                v = *(const float4*)(xc + (size_t)gi * IMG_W + c4);
        }
        pf[u] = v;
    }
}

// write y = s*x+m to LDS (pitch P dwords) from prefetched regs; pad rows -> 0 (kB)
__device__ __forceinline__ void stage_write(float s, float m, int r0, int t,
                                            const float4* pf, float* __restrict__ Y,
                                            int P) {
#pragma unroll
    for (int u = 0; u < 4; ++u) {
        const int idx = t + 256 * u;
        if (idx < 896) {
            const int row = idx / 56, c4 = (idx % 56) * 4;
            const int gi = r0 - 1 + row;
            float4 w;
            if (gi >= 0 && gi < IMG_H) {
                w.x = FA(FM(pf[u].x, s), m);
                w.y = FA(FM(pf[u].y, s), m);
                w.z = FA(FM(pf[u].z, s), m);
                w.w = FA(FM(pf[u].w, s), m);
            } else {
                w.x = w.y = w.z = w.w = 0.0f;
            }
            *(float4*)(&Y[row * P + c4]) = w;
        }
    }
}

// 6 y-taps from LDS (kB only; pitch 224): aligned float4 reads
__device__ __forceinline__ void lds_y6(const float* __restrict__ r, int j, float* y6) {
    const float4 vC = *(const float4*)(r + j);
    const float4 vL = *(const float4*)(r + (j > 0 ? j - 4 : 0));
    const float4 vR = *(const float4*)(r + (j + 4 < IMG_W ? j + 4 : IMG_W - 4));
    y6[0] = (j > 0) ? vL.w : 0.0f;
    y6[1] = vC.x; y6[2] = vC.y; y6[3] = vC.z; y6[4] = vC.w;
    y6[5] = (j + 4 < IMG_W) ? vR.x : 0.0f;
}

// ---- Kernel A1 (7-row chunks): one block = one 1568-px chunk = 16 aligned
// leaves of the numpy pairwise tree (16 | 512). GRAY-FIRST; lean staging
// (fold gray per iteration, ~6 f4 in flight) so VGPR <= 64 at
// launch_bounds(256,8) -> 8 blocks/CU, 100% occupancy. LDS 8.2 KB.
__global__ __launch_bounds__(256, 8) void kA1(const float* __restrict__ x,
                                              const float* __restrict__ mean_,
                                              const float* __restrict__ std_,
                                              float* __restrict__ part) {
    // bijective XCD swizzle (8192 % 8 == 0): each XCD gets 32 whole images
    const int swz = ((int)blockIdx.x & 7) * 1024 + ((int)blockIdx.x >> 3);
    const int ck = swz & 31, b = swz >> 5;
    const int t = threadIdx.x;
    const int r0 = ck * 7;

    __shared__ float SM[2052];        // 8208 B: Y[9][YP]; G2/CH alias after
    float* Y  = SM;
    float* G2 = SM;                   // [0,1664) 16 leaves x 104
    float* CH = SM + 1664;            // [1664,1792)

    const int rg  = t / 56;           // row-group 0..3 (rows 2,2,2,1)
    const int col = t - rg * 56;
    const bool active = (t < 224);
    const int rcount = (rg < 3) ? 2 : 1;
    const int rstart = rg * 2;        // 0,2,4,6
    const int jd = col * 4;
    const bool lwave = ((t & 63) == 0)  && (col > 0);
    const bool rwave = ((t & 63) == 63) && (col < 55);

    const float s0 = std_[0], s1 = std_[1], s2 = std_[2];
    const float m0 = mean_[0], m1 = mean_[1], m2 = mean_[2];
    const float C0 = 0.299f, C1 = 0.587f, C2 = 0.114f;

#define GRAY1(a0v, a1v, a2v)                                              \
    FA(FA(FM(C0, FA(FM(a0v, s0), m0)), FM(C1, FA(FM(a1v, s1), m1))),      \
       FM(C2, FA(FM(a2v, s2), m2)))

    // ---- stage: 504 quads (9 rows x 56), gray folded per iteration ----
#pragma unroll
    for (int u = 0; u < 2; ++u) {
        const int idx = t + 256 * u;
        if (idx < 504) {
            const int row = idx / 56, c4 = (idx % 56) * 4;
            const int gi = r0 - 1 + row;
            float4 w = make_float4(0.f, 0.f, 0.f, 0.f);
            if (gi >= 0 && gi < IMG_H) {
                const float* p = x + (size_t)b * 3 * HWPIX + (size_t)gi * IMG_W + c4;
                const float4 qa = *(const float4*)(p);
                const float4 qb = *(const float4*)(p + HWPIX);
                const float4 qc = *(const float4*)(p + 2 * HWPIX);
                w.x = GRAY1(qa.x, qb.x, qc.x);
                w.y = GRAY1(qa.y, qb.y, qc.y);
                w.z = GRAY1(qa.z, qb.z, qc.z);
                w.w = GRAY1(qa.w, qb.w, qc.w);
            }
            *(float4*)(&Y[row * YP + c4]) = w;
        }
    }
#undef GRAY1
    __syncthreads();

#define LOADROW(V, LWv, RWv, yr) do {                                 \
        V   = *(const float4*)(&Y[(yr) * YP + jd]);                   \
        LWv = __shfl_up(V.w, 1, 64);                                  \
        RWv = __shfl_down(V.x, 1, 64);                                \
        if (lwave) LWv = Y[(yr) * YP + jd - 1];                       \
        if (rwave) RWv = Y[(yr) * YP + jd + 4];                       \
    } while (0)

#define FILL6(y6, V, LWv, RWv) do {                                   \
        y6[0] = (col > 0) ? LWv : 0.0f;                               \
        y6[1] = V.x; y6[2] = V.y; y6[3] = V.z; y6[4] = V.w;           \
        y6[5] = (col < 55) ? RWv : 0.0f;                              \
    } while (0)

    float4 gacc[2];

    // ---- column sweep: gacc = gray(y1) for this thread's rows ----
    if (active) {
        float4 v0, v1, v2;
        float la0, la1, la2, ra0, ra1, ra2;
        LOADROW(v0, la0, ra0, rstart);
        LOADROW(v1, la1, ra1, rstart + 1);
#pragma unroll
        for (int k = 0; k < 2; ++k) {
            if (k < rcount) {
                LOADROW(v2, la2, ra2, rstart + k + 2);
                float yU[6], yC[6], yD[6], y1g[4];
                FILL6(yU, v0, la0, ra0);
                FILL6(yC, v1, la1, ra1);
                FILL6(yD, v2, la2, ra2);
                y1_from_rows(yU, yC, yD, y1g);
                gacc[k].x = y1g[0]; gacc[k].y = y1g[1];
                gacc[k].z = y1g[2]; gacc[k].w = y1g[3];
                v0 = v1; la0 = la1; ra0 = ra1;
                v1 = v2; la1 = la2; ra1 = ra2;
            }
        }
    }
    __syncthreads();   // Y dead -> G2 alias handoff

    // ---- write gray(y1) into leaf-padded G2 (16 leaves x 104) ----
    if (active) {
#pragma unroll
        for (int k = 0; k < 2; ++k) {
            if (k < rcount) {
                const int pl = (rstart + k) * IMG_W + jd;   // [0,1568)
                const int grp = pl / 392;                   // 0..3
                const int rem = pl - grp * 392;
                int li = rem / 96; if (li > 3) li = 3;
                const int o = rem - 96 * li;
                *(float4*)(&G2[(grp * 4 + li) * 104 + o]) = gacc[k];
            }
        }
    }
    __syncthreads();

    // ---- 8 chains per leaf, 16 leaves (exact numpy base case) ----
    if (t < 128) {
        const int leaf = t >> 3, e = t & 7;
        const int base = leaf * 104 + e;
        const int nk = ((leaf & 3) == 3) ? 13 : 12;
        float r = G2[base];
        for (int k = 1; k < nk; ++k) r = FA(r, G2[base + 8 * k]);
        CH[t] = r;   // t == leaf*8+e
    }
    __syncthreads();

    // ---- leaf sums + exact 4-level binary tree via shfl (bit-exact pairing) ----
    if (t < 16) {
        const float* c8 = &CH[t * 8];
        float vv = FA(FA(FA(c8[0], c8[1]), FA(c8[2], c8[3])),
                      FA(FA(c8[4], c8[5]), FA(c8[6], c8[7])));
#pragma unroll
        for (int n = 8; n >= 1; n >>= 1) {
            const float lo = __shfl(vv, 2 * t, 64);
            const float hi = __shfl(vv, 2 * t + 1, 64);
            vv = FA(lo, hi);
        }
        if (t == 0) part[swz] = vv;
    }
#undef LOADROW
#undef FILL6
}

// ---- Kernel B (R19 structure, reg-staged): 1-D grid (12288 blocks), XCD
// swizzle; one block = one 14-row chunk of one (b,c). gm = exact 5-level fold
// of 32 chunk roots, hoisted to overlap the x-load latency. NT stores. ----
__global__ __launch_bounds__(256) void kB(const float* __restrict__ x,
                                          const float* __restrict__ mean_,
                                          const float* __restrict__ std_,
                                          const float* __restrict__ part,
                                          float* __restrict__ out) {
    // bijective XCD swizzle (12288 % 8 == 0)
    const int swz = ((int)blockIdx.x & 7) * 1536 + ((int)blockIdx.x >> 3);
    const int ck = swz & 15;
    const int r1 = swz >> 4;
    const int c  = r1 % 3;
    const int b  = r1 / 3;
    const int t  = threadIdx.x;
    const int r0 = ck * 14;

    __shared__ float Y[16 * IMG_W];
    __shared__ float gsh;

    const float s = std_[c], m = mean_[c];
    float4 pf[4];
    stage_load(x + (size_t)(b * 3 + c) * HWPIX, r0, t, pf);

    if (t == 0) {
        // exact 5-level fold of the 32 chunk roots, / 50176
        // (issued while the x stage loads are still in flight)
        float v[32];
#pragma unroll
        for (int k = 0; k < 32; ++k) v[k] = part[b * 32 + k];
#pragma unroll
        for (int n = 16; n >= 1; n >>= 1)
#pragma unroll
            for (int k = 0; k < 16; ++k)
                if (k < n) v[k] = FA(v[2 * k], v[2 * k + 1]);
        gsh = FD(v[0], 50176.0f);
    }

    stage_write(s, m, r0, t, pf, Y, IMG_W);
    __syncthreads();
    const float g = gsh;

    float* oc = out + (size_t)(b * 3 + c) * HWPIX + (size_t)r0 * IMG_W;

    for (int qi = t; qi < 784; qi += 256) {
        const int lr = qi / 56 + 1, j = (qi % 56) * 4;
        float yU[6], yC[6], yD[6], y1[4];
        lds_y6(&Y[(lr - 1) * IMG_W], j, yU);
        lds_y6(&Y[lr * IMG_W],       j, yC);
        lds_y6(&Y[(lr + 1) * IMG_W], j, yD);
        y1_from_rows(yU, yC, yD, y1);

        nt4 o4;
#pragma unroll
        for (int mm = 0; mm < 4; ++mm) {
            const float y2 = FA(FM(y1[mm], VBF()), FM(g, OMVBF()));
            const float y3 = FM(y2, VBF());
            const float y4 = (y3 < VSF()) ? y3 : FS(1.0f, y3);
            o4[mm] = FD(FS(y4, m), s);
        }
        __builtin_nontemporal_store(o4, (nt4*)(oc + (size_t)(lr - 1) * IMG_W + j));
    }
}

extern "C" void kernel_launch(void* const* d_in, const int* in_sizes, int n_in,
                              void* d_out, int out_size, void* d_ws, size_t ws_size,
                              hipStream_t stream) {
    const float* x     = (const float*)d_in[0];
    const float* mean_ = (const float*)d_in[1];
    const float* std_  = (const float*)d_in[2];
    float* out = (float*)d_out;

    float* part = (float*)d_ws;   // 8192 f32 (32 chunk roots x 256 images)

    kA1<<<IMG_B * 32, 256, 0, stream>>>(x, mean_, std_, part);

    kB<<<IMG_B * 3 * 16, 256, 0, stream>>>(x, mean_, std_, part, out);
}